// Round 2
// baseline (683.982 us; speedup 1.0000x reference)
//
#include <hip/hip_runtime.h>

typedef __bf16 bf16;
typedef __bf16 bf16x8 __attribute__((ext_vector_type(8)));
typedef __bf16 bf16x4 __attribute__((ext_vector_type(4)));
typedef float  f32x4  __attribute__((ext_vector_type(4)));

#define EPSBN 1e-5f

// ---------------- async global->LDS (16B per lane) ----------------
__device__ __forceinline__ void gload16(const void* gp, void* lp) {
  __builtin_amdgcn_global_load_lds(
      (__attribute__((address_space(1))) void*)(unsigned long long)gp,
      (__attribute__((address_space(3))) void*)(unsigned)(unsigned long long)lp,
      16, 0, 0);
}

// ---------------- k_prep: cast wa/wc to bf16, fold BN params, zero counters ----------------
__global__ __launch_bounds__(256) void k_prep(
    const float* __restrict__ wa, const float* __restrict__ wc,
    const float* __restrict__ ga, const float* __restrict__ ba, const float* __restrict__ ma, const float* __restrict__ va,
    const float* __restrict__ gb, const float* __restrict__ bb, const float* __restrict__ mb, const float* __restrict__ vb,
    const float* __restrict__ gc, const float* __restrict__ bc, const float* __restrict__ mc, const float* __restrict__ vc,
    bf16* __restrict__ wa_bf, bf16* __restrict__ wc_bf, float* __restrict__ bn6,
    unsigned* __restrict__ cnts)
{
  unsigned i = blockIdx.x * 256 + threadIdx.x;   // 262144 threads
  unsigned e = i * 4;
  float4 a = *(const float4*)(wa + e);
  bf16x4 av; av[0]=(bf16)a.x; av[1]=(bf16)a.y; av[2]=(bf16)a.z; av[3]=(bf16)a.w;
  *(bf16x4*)(wa_bf + e) = av;
  float4 c = *(const float4*)(wc + e);
  bf16x4 cv; cv[0]=(bf16)c.x; cv[1]=(bf16)c.y; cv[2]=(bf16)c.z; cv[3]=(bf16)c.w;
  *(bf16x4*)(wc_bf + e) = cv;
  if (i < 1024) {
    float s;
    s = ga[i] / sqrtf(va[i] + EPSBN); bn6[i]        = s; bn6[1024 + i] = ba[i] - ma[i] * s;
    s = gb[i] / sqrtf(vb[i] + EPSBN); bn6[2048 + i] = s; bn6[3072 + i] = bb[i] - mb[i] * s;
    s = gc[i] / sqrtf(vc[i] + EPSBN); bn6[4096 + i] = s; bn6[5120 + i] = bc[i] - mc[i] * s;
  }
  if (i == 0) { cnts[0] = 0u; cnts[1] = 0u; }
}

// ---------------- k_ring: zero the 1-pixel pad ring of h1p [32][30][30][1024] ----------------
__global__ __launch_bounds__(256) void k_ring(bf16* __restrict__ h1p)
{
  int t = blockIdx.x * 256 + threadIdx.x;        // 475136 = 32*116*128
  int c8 = t & 127;
  int r  = (t >> 7) % 116;
  int b  = t / (116 * 128);
  int y, x;
  if (r < 30)      { y = 0;      x = r; }
  else if (r < 60) { y = 29;     x = r - 30; }
  else if (r < 88) { y = r - 59; x = 0; }
  else             { y = r - 87; x = 29; }
  size_t off = (((size_t)b * 30 + y) * 30 + x) * 1024 + (size_t)c8 * 8;
  *(uint4*)(h1p + off) = uint4{0, 0, 0, 0};
}

// ---------------- k_cast_pool: x NCHW fp32 -> xT [P][1024] bf16, + 4x4 avgpool (fp32) ----------------
__global__ __launch_bounds__(256) void k_cast_pool(
    const float* __restrict__ x, bf16* __restrict__ xT, float* __restrict__ pooled)
{
  const int pt = blockIdx.x, ct = blockIdx.y, b = blockIdx.z;   // 7,16,32
  __shared__ float tile[64 * 116];
  const int tid = threadIdx.x;
  const float* src = x + ((size_t)(b * 1024 + ct * 64)) * 784 + pt * 112;
  #pragma unroll
  for (int it = 0; it < 7; it++) {
    unsigned f = tid + it * 256;            // 0..1791 : 64 rows x 28 float4
    unsigned ci = f / 28, j = f % 28;
    float4 v = *(const float4*)(src + (size_t)ci * 784 + j * 4);
    *(float4*)(tile + ci * 116 + j * 4) = v;
  }
  __syncthreads();
  // transposed bf16 write: per pixel j, 64 channels contiguous
  bf16* dst = xT + ((size_t)(b * 784 + pt * 112)) * 1024 + ct * 64;
  for (int s = tid; s < 896; s += 256) {
    int j = s >> 3, c8 = s & 7;
    bf16x8 tmp;
    #pragma unroll
    for (int e = 0; e < 8; e++) tmp[e] = (bf16)tile[(c8 * 8 + e) * 116 + j];
    *(bf16x8*)(dst + (size_t)j * 1024 + c8 * 8) = tmp;
  }
  // pooled[b][c][pt*7+ox] : exact fp32
  for (int s = tid; s < 448; s += 256) {
    int c = s / 7, ox = s % 7;
    float acc = 0.f;
    #pragma unroll
    for (int yy = 0; yy < 4; yy++)
      #pragma unroll
      for (int xx = 0; xx < 4; xx++)
        acc += tile[c * 116 + yy * 28 + ox * 4 + xx];
    pooled[((size_t)(b * 1024 + ct * 64 + c)) * 49 + pt * 7 + ox] = acc * (1.0f / 16.0f);
  }
}

// ---------------- k_mask: logits, mask7, dilation, counts (all fp32) ----------------
__global__ __launch_bounds__(128) void k_mask(
    const float* __restrict__ pooled, const float* __restrict__ mkw, const float* __restrict__ mkb,
    float* __restrict__ mask7, unsigned* __restrict__ cnts)
{
  const int b = blockIdx.x, tid = threadIdx.x;
  __shared__ float l0s[49], l1s[49];
  __shared__ unsigned char m7[49];
  const int j = tid >> 6, p = tid & 63;
  if (p < 49) {
    const float* pb = pooled + (size_t)b * 1024 * 49 + p;
    const float* wr = mkw + j * 1024;
    float acc = 0.f;
    #pragma unroll 8
    for (int c = 0; c < 1024; c++) acc += pb[(size_t)c * 49] * wr[c];
    acc += mkb[j];
    if (j == 0) l0s[p] = acc; else l1s[p] = acc;
  }
  __syncthreads();
  if (tid < 49) {
    unsigned char m = (l0s[tid] >= l1s[tid]) ? 1 : 0;
    m7[tid] = m;
    mask7[b * 49 + tid] = (float)m;
  }
  __syncthreads();
  if (tid < 64) {
    unsigned long long bal = __ballot((tid < 49) && m7[tid]);
    if (tid == 0) atomicAdd(&cnts[0], (unsigned)__popcll(bal));
  }
  int cnt = 0;
  for (int p2 = tid; p2 < 784; p2 += 128) {
    int y = p2 / 28, x = p2 % 28;
    int cy0 = (y == 0) ? 0 : (y - 1) >> 2, cy1 = (y == 27) ? 6 : (y + 1) >> 2;
    int cx0 = (x == 0) ? 0 : (x - 1) >> 2, cx1 = (x == 27) ? 6 : (x + 1) >> 2;
    int d = 0;
    for (int cy = cy0; cy <= cy1; cy++)
      for (int cx = cx0; cx <= cx1; cx++) d |= m7[cy * 7 + cx];
    cnt += d;
  }
  cnt += __shfl_xor(cnt, 1);  cnt += __shfl_xor(cnt, 2);  cnt += __shfl_xor(cnt, 4);
  cnt += __shfl_xor(cnt, 8);  cnt += __shfl_xor(cnt, 16); cnt += __shfl_xor(cnt, 32);
  __shared__ int wsum[2];
  if ((tid & 63) == 0) wsum[tid >> 6] = cnt;
  __syncthreads();
  if (tid == 0) atomicAdd(&cnts[1], (unsigned)(wsum[0] + wsum[1]));
}

// ---------------- k_fin: scalar outputs ----------------
__global__ void k_fin(const unsigned* __restrict__ cnts, float* __restrict__ tail)
{
  if (threadIdx.x == 0 && blockIdx.x == 0) {
    float sp = (float)cnts[0] / 1568.0f;
    float sd = (float)cnts[1] / 25088.0f;
    const float c1 = 1048576.0f, c2 = 589824.0f, c3 = 1048576.0f, mf = 200704.0f;
    float dense  = mf + (c1 + c2 + c3) * 784.0f;
    float sparse = mf + c1 * 784.0f * sd + (c2 + c3) * 784.0f * sp;
    tail[0] = sp; tail[1] = sd; tail[2] = sparse / dense; tail[3] = sparse;
  }
}

// ---------------- k_gemm: D[m][n] = sum_k A[m][k]*B[n][k], 128x128 tile, BK=64 ----------------
// MODE 0 (conv_a): A=xT (m=pixel), B=wa_bf (n=co), out = h1p bf16 NHWC padded, BN_a+ReLU
// MODE 1 (conv_c): A=wc_bf (m=co), B=h2T (n=pixel), out = final fp32 NCHW, BN_c+mask+residual+ReLU
template<int MODE>
__global__ __launch_bounds__(256) void k_gemm(
    const bf16* __restrict__ Aop, const bf16* __restrict__ Bop, void* __restrict__ outp,
    const float* __restrict__ bn6, const float* __restrict__ xres, const float* __restrict__ mask7)
{
  const int mt = blockIdx.x, nt = blockIdx.y;
  __shared__ bf16 ldsA[8192];   // 128 x 64, xor-swizzled chunks
  __shared__ bf16 ldsB[8192];
  const int tid = threadIdx.x, lane = tid & 63, w = tid >> 6;
  const int wm = w & 1, wn = w >> 1;
  const int li = lane & 15, q = lane >> 4;

  const bf16* Ab = Aop + (size_t)mt * 128 * 1024;
  const bf16* Bb = Bop + (size_t)nt * 128 * 1024;
  const bf16* ga[4]; const bf16* gb[4];
  #pragma unroll
  for (int j = 0; j < 4; j++) {
    int c = w * 256 + j * 64 + lane;
    int row = c >> 3, k8 = (c & 7) ^ (row & 7);
    ga[j] = Ab + (size_t)row * 1024 + k8 * 8;
    gb[j] = Bb + (size_t)row * 1024 + k8 * 8;
  }
  const int lb = li * 128 + ((q ^ (li & 7)) << 4);   // lane frag byte base
  f32x4 acc[4][4] = {};

  for (int kt = 0; kt < 16; kt++) {
    #pragma unroll
    for (int j = 0; j < 4; j++) gload16(ga[j], (char*)ldsA + w * 4096 + j * 1024);
    #pragma unroll
    for (int j = 0; j < 4; j++) gload16(gb[j], (char*)ldsB + w * 4096 + j * 1024);
    #pragma unroll
    for (int j = 0; j < 4; j++) { ga[j] += 64; gb[j] += 64; }
    __syncthreads();
    #pragma unroll
    for (int ks = 0; ks < 2; ks++) {
      bf16x8 af[4], bfr[4];
      #pragma unroll
      for (int m = 0; m < 4; m++)
        af[m] = *(const bf16x8*)((const char*)ldsA + wm * 8192 + m * 2048 + (lb ^ (ks * 64)));
      #pragma unroll
      for (int n = 0; n < 4; n++)
        bfr[n] = *(const bf16x8*)((const char*)ldsB + wn * 8192 + n * 2048 + (lb ^ (ks * 64)));
      #pragma unroll
      for (int m = 0; m < 4; m++)
        #pragma unroll
        for (int n = 0; n < 4; n++)
          acc[m][n] = __builtin_amdgcn_mfma_f32_16x16x32_bf16(af[m], bfr[n], acc[m][n], 0, 0, 0);
    }
    __syncthreads();
  }

  if constexpr (MODE == 0) {
    bf16* h1p = (bf16*)outp;
    const float* sa  = bn6;
    const float* ba2 = bn6 + 1024;
    const int p_base  = mt * 128 + wm * 64 + q * 4;
    const int co_base = nt * 128 + wn * 64 + li;
    #pragma unroll
    for (int n = 0; n < 4; n++) {
      int co = co_base + n * 16;
      float s = sa[co], o = ba2[co];
      #pragma unroll
      for (int m = 0; m < 4; m++) {
        #pragma unroll
        for (int r = 0; r < 4; r++) {
          unsigned p = p_base + m * 16 + r;
          unsigned b = p / 784u, rem = p % 784u;
          unsigned y = rem / 28u, xx = rem % 28u;
          float v = fmaxf(acc[m][n][r] * s + o, 0.f);
          h1p[(((size_t)b * 30 + y + 1) * 30 + xx + 1) * 1024 + co] = (bf16)v;
        }
      }
    }
  } else {
    float* dst = (float*)outp;
    const float* sc  = bn6 + 4096;
    const float* bc2 = bn6 + 5120;
    const int co_base = mt * 128 + wm * 64 + q * 4;
    const int p_base  = nt * 128 + wn * 64 + li;
    #pragma unroll
    for (int n = 0; n < 4; n++) {
      unsigned p = p_base + n * 16;
      unsigned b = p / 784u, rem = p % 784u;
      unsigned y = rem / 28u, xx = rem % 28u;
      float mv = mask7[b * 49 + (y >> 2) * 7 + (xx >> 2)];
      const float* xp = xres + (size_t)b * 1024 * 784 + rem;
      float*       op = dst  + (size_t)b * 1024 * 784 + rem;
      #pragma unroll
      for (int m = 0; m < 4; m++) {
        #pragma unroll
        for (int r = 0; r < 4; r++) {
          int co = co_base + m * 16 + r;
          float v = acc[m][n][r] * sc[co] + bc2[co];
          v = v * mv + xp[(size_t)co * 784];
          op[(size_t)co * 784] = fmaxf(v, 0.f);
        }
      }
    }
  }
}

// ---------------- k_conv_b: grouped 3x3 + BN + ReLU + SE partial sums ----------------
__global__ __launch_bounds__(256) void k_conv_b(
    const bf16* __restrict__ h1p, const float* __restrict__ wb,
    bf16* __restrict__ h2T, float* __restrict__ sums, const float* __restrict__ bn6)
{
  const int b = blockIdx.x, g = blockIdx.y;
  __shared__ bf16 ldsI[184 * 64];     // 23552 B, xor-swizzled [pos][ci]
  const int tid = threadIdx.x, lane = tid & 63, w = tid >> 6;
  const int li = lane & 15, q = lane >> 4;

  // weights into registers: lane holds co=g*64+w*16+li, k = cs*32+q*8+j
  bf16x8 wreg[9][2];
  {
    const float* wsrc = wb + ((size_t)(g * 64 + w * 16 + li)) * 576;  // [ci][3][3]
    #pragma unroll
    for (int cs = 0; cs < 2; cs++)
      #pragma unroll
      for (int jj = 0; jj < 8; jj++) {
        int ci = cs * 32 + q * 8 + jj;
        #pragma unroll
        for (int kk = 0; kk < 9; kk++)
          wreg[kk][cs][jj] = (bf16)wsrc[ci * 9 + kk];
      }
  }

  // staging offsets: 23 wave-instrs over block, wave w does j = w, w+4, ...
  int offs[6];
  #pragma unroll
  for (int t = 0; t < 6; t++) {
    int j = w + t * 4;
    int c = j * 64 + lane;
    int pos = c >> 3, ci8 = (c & 7) ^ (pos & 7);
    offs[t] = (j < 23) ? pos * 1024 + ci8 * 8 : 0;
  }
  const bf16* iBase = h1p + (size_t)b * 900 * 1024 + g * 64;

  int pos0[7];
  #pragma unroll
  for (int mtt = 0; mtt < 7; mtt++) {
    int n = mtt * 16 + li;
    pos0[mtt] = (n / 28) * 30 + (n % 28);
  }
  const int co = g * 64 + w * 16 + li;
  const float sb  = bn6[2048 + co];
  const float bb2 = bn6[3072 + co];
  float csum = 0.f;
  bf16* outBase = h2T + (size_t)b * 784 * 1024 + co;

  for (int yt = 0; yt < 7; yt++) {
    #pragma unroll
    for (int t = 0; t < 6; t++) {
      int j = w + t * 4;
      // clamp: at yt==6 only 180 positions exist in the padded image; skip the
      // tail chunks (LDS pos 180..183 are never read by the compute loop)
      if (j < 23 && (yt < 6 || j < 22 || lane < 32))
        gload16(iBase + (size_t)yt * 122880 + offs[t], (char*)ldsI + j * 1024);
    }
    __syncthreads();
    f32x4 acc[7] = {};
    #pragma unroll
    for (int kk = 0; kk < 9; kk++) {
      const int shift = (kk / 3) * 30 + (kk % 3);
      #pragma unroll
      for (int cs = 0; cs < 2; cs++) {
        #pragma unroll
        for (int mtt = 0; mtt < 7; mtt++) {
          int pos = pos0[mtt] + shift;
          int off = pos * 128 + ((((cs << 2) + q) ^ (pos & 7)) << 4);
          bf16x8 a = *(const bf16x8*)((const char*)ldsI + off);
          acc[mtt] = __builtin_amdgcn_mfma_f32_16x16x32_bf16(a, wreg[kk][cs], acc[mtt], 0, 0, 0);
        }
      }
    }
    __syncthreads();
    #pragma unroll
    for (int mtt = 0; mtt < 7; mtt++) {
      #pragma unroll
      for (int r = 0; r < 4; r++) {
        int pl = mtt * 16 + q * 4 + r;
        float v = fmaxf(acc[mtt][r] * sb + bb2, 0.f);
        csum += v;
        outBase[((size_t)yt * 112 + pl) * 1024] = (bf16)v;
      }
    }
  }
  csum += __shfl_xor(csum, 16);
  csum += __shfl_xor(csum, 32);
  if (q == 0) sums[b * 1024 + co] = csum;
}

// ---------------- k_se: squeeze-excite MLP (fp32) ----------------
__global__ __launch_bounds__(256) void k_se(
    const float* __restrict__ sums, const float* __restrict__ sw1, const float* __restrict__ sb1,
    const float* __restrict__ sw2, const float* __restrict__ sb2, float* __restrict__ s2)
{
  const int b = blockIdx.x, tid = threadIdx.x;
  __shared__ float mean[1024];
  __shared__ float s1[256];
  for (int i = tid; i < 1024; i += 256) mean[i] = sums[b * 1024 + i] * (1.0f / 784.0f);
  __syncthreads();
  {
    float acc = sb1[tid];
    const float4* wr = (const float4*)(sw1 + (size_t)tid * 1024);
    #pragma unroll 4
    for (int c4 = 0; c4 < 256; c4++) {
      float4 wv = wr[c4];
      acc += wv.x * mean[c4 * 4] + wv.y * mean[c4 * 4 + 1] + wv.z * mean[c4 * 4 + 2] + wv.w * mean[c4 * 4 + 3];
    }
    s1[tid] = fmaxf(acc, 0.f);
  }
  __syncthreads();
  for (int co = tid; co < 1024; co += 256) {
    float acc = sb2[co];
    const float4* wr = (const float4*)(sw2 + (size_t)co * 256);
    #pragma unroll 4
    for (int q4 = 0; q4 < 64; q4++) {
      float4 wv = wr[q4];
      acc += wv.x * s1[q4 * 4] + wv.y * s1[q4 * 4 + 1] + wv.z * s1[q4 * 4 + 2] + wv.w * s1[q4 * 4 + 3];
    }
    s2[b * 1024 + co] = 1.0f / (1.0f + __expf(-acc));
  }
}

// ---------------- k_scale: h2T *= s2 (in place) ----------------
__global__ __launch_bounds__(256) void k_scale(bf16* __restrict__ h2T, const float* __restrict__ s2)
{
  size_t idx = ((size_t)blockIdx.x * 256 + threadIdx.x) * 8;
  unsigned b = (unsigned)(idx / 802816u);         // 784*1024
  unsigned c = (unsigned)(idx & 1023u);
  const float* sp = s2 + b * 1024 + c;
  bf16x8 v = *(const bf16x8*)(h2T + idx);
  #pragma unroll
  for (int e = 0; e < 8; e++) v[e] = (bf16)((float)v[e] * sp[e]);
  *(bf16x8*)(h2T + idx) = v;
}

// ---------------- launch ----------------
extern "C" void kernel_launch(void* const* d_in, const int* in_sizes, int n_in,
                              void* d_out, int out_size, void* d_ws, size_t ws_size,
                              hipStream_t stream)
{
  const float* x   = (const float*)d_in[0];
  const float* wa  = (const float*)d_in[2];
  const float* ga  = (const float*)d_in[3];
  const float* ba  = (const float*)d_in[4];
  const float* ma  = (const float*)d_in[5];
  const float* va  = (const float*)d_in[6];
  const float* wb  = (const float*)d_in[7];
  const float* gb  = (const float*)d_in[8];
  const float* bb  = (const float*)d_in[9];
  const float* mb  = (const float*)d_in[10];
  const float* vb  = (const float*)d_in[11];
  const float* sw1 = (const float*)d_in[12];
  const float* sb1 = (const float*)d_in[13];
  const float* sw2 = (const float*)d_in[14];
  const float* sb2 = (const float*)d_in[15];
  const float* wc  = (const float*)d_in[16];
  const float* gc  = (const float*)d_in[17];
  const float* bc  = (const float*)d_in[18];
  const float* mc  = (const float*)d_in[19];
  const float* vc  = (const float*)d_in[20];
  const float* mkw = (const float*)d_in[21];
  const float* mkb = (const float*)d_in[22];

  char* ws = (char*)d_ws;
  bf16*  xT     = (bf16*)(ws + 0);              // 51,380,224 B  (reused as h2T)
  bf16*  h1p    = (bf16*)(ws + 51380224);       // 58,982,400 B + 65,536 slack
  bf16*  wa_bf  = (bf16*)(ws + 110428160);      // 2,097,152
  bf16*  wc_bf  = (bf16*)(ws + 112525312);      // 2,097,152
  float* pooled = (float*)(ws + 114622464);     // 6,422,528
  float* mask7  = (float*)(ws + 121044992);     // 8,192
  float* sums   = (float*)(ws + 121053184);     // 131,072
  float* s2     = (float*)(ws + 121184256);     // 131,072
  float* bn6    = (float*)(ws + 121315328);     // 24,576
  unsigned* cnts = (unsigned*)(ws + 121339904); // 8

  float* out = (float*)d_out;

  k_prep<<<1024, 256, 0, stream>>>(wa, wc, ga, ba, ma, va, gb, bb, mb, vb, gc, bc, mc, vc, wa_bf, wc_bf, bn6, cnts);
  k_ring<<<1856, 256, 0, stream>>>(h1p);
  k_cast_pool<<<dim3(7, 16, 32), 256, 0, stream>>>(x, xT, pooled);
  k_mask<<<32, 128, 0, stream>>>(pooled, mkw, mkb, mask7, cnts);
  k_fin<<<1, 64, 0, stream>>>(cnts, out + 25690112);
  k_gemm<0><<<dim3(196, 8), 256, 0, stream>>>(xT, wa_bf, h1p, bn6, nullptr, nullptr);
  k_conv_b<<<dim3(32, 16), 256, 0, stream>>>(h1p, wb, xT /*h2T*/, sums, bn6);
  k_se<<<32, 256, 0, stream>>>(sums, sw1, sb1, sw2, sb2, s2);
  k_scale<<<12544, 256, 0, stream>>>(xT, s2);
  k_gemm<1><<<dim3(8, 196), 256, 0, stream>>>(wc_bf, xT, out, bn6, x, mask7);
}

// Round 3
// 617.857 us; speedup vs baseline: 1.1070x; 1.1070x over previous
//
#include <hip/hip_runtime.h>

typedef __bf16 bf16;
typedef __bf16 bf16x8 __attribute__((ext_vector_type(8)));
typedef __bf16 bf16x4 __attribute__((ext_vector_type(4)));
typedef float  f32x4  __attribute__((ext_vector_type(4)));

#define EPSBN 1e-5f

// ---------------- async global->LDS (16B per lane) ----------------
__device__ __forceinline__ void gload16(const void* gp, void* lp) {
  __builtin_amdgcn_global_load_lds(
      (__attribute__((address_space(1))) void*)(unsigned long long)gp,
      (__attribute__((address_space(3))) void*)(unsigned)(unsigned long long)lp,
      16, 0, 0);
}

// ---------------- k_prep: cast wa/wc to bf16, fold BN params, zero counters+sums ----------------
__global__ __launch_bounds__(256) void k_prep(
    const float* __restrict__ wa, const float* __restrict__ wc,
    const float* __restrict__ ga, const float* __restrict__ ba, const float* __restrict__ ma, const float* __restrict__ va,
    const float* __restrict__ gb, const float* __restrict__ bb, const float* __restrict__ mb, const float* __restrict__ vb,
    const float* __restrict__ gc, const float* __restrict__ bc, const float* __restrict__ mc, const float* __restrict__ vc,
    bf16* __restrict__ wa_bf, bf16* __restrict__ wc_bf, float* __restrict__ bn6,
    float* __restrict__ sums, unsigned* __restrict__ cnts)
{
  unsigned i = blockIdx.x * 256 + threadIdx.x;   // 262144 threads
  unsigned e = i * 4;
  float4 a = *(const float4*)(wa + e);
  bf16x4 av; av[0]=(bf16)a.x; av[1]=(bf16)a.y; av[2]=(bf16)a.z; av[3]=(bf16)a.w;
  *(bf16x4*)(wa_bf + e) = av;
  float4 c = *(const float4*)(wc + e);
  bf16x4 cv; cv[0]=(bf16)c.x; cv[1]=(bf16)c.y; cv[2]=(bf16)c.z; cv[3]=(bf16)c.w;
  *(bf16x4*)(wc_bf + e) = cv;
  if (i < 1024) {
    float s;
    s = ga[i] / sqrtf(va[i] + EPSBN); bn6[i]        = s; bn6[1024 + i] = ba[i] - ma[i] * s;
    s = gb[i] / sqrtf(vb[i] + EPSBN); bn6[2048 + i] = s; bn6[3072 + i] = bb[i] - mb[i] * s;
    s = gc[i] / sqrtf(vc[i] + EPSBN); bn6[4096 + i] = s; bn6[5120 + i] = bc[i] - mc[i] * s;
  }
  if (i < 32768) sums[i] = 0.f;
  if (i == 0) { cnts[0] = 0u; cnts[1] = 0u; }
}

// ---------------- k_prepw: wb fp32 [co][ci][3][3] -> bf16 frag layout [g*9+kk][co%64][ci] ----------------
__global__ __launch_bounds__(256) void k_prepw(const float* __restrict__ wb, bf16* __restrict__ wb_bf)
{
  int t = blockIdx.x * 256 + threadIdx.x;    // 589824
  int ci = t & 63;
  int u  = t >> 6;
  int cl = u & 63;
  int gk = u >> 6;           // g*9 + kk
  int g  = gk / 9, kk = gk - g * 9;
  wb_bf[t] = (bf16)wb[(((size_t)(g * 64 + cl) * 64) + ci) * 9 + kk];
}

// ---------------- k_ring: zero the 1-pixel pad ring of h1p [32][30][30][1024] ----------------
__global__ __launch_bounds__(256) void k_ring(bf16* __restrict__ h1p)
{
  int t = blockIdx.x * 256 + threadIdx.x;        // 475136 = 32*116*128
  int c8 = t & 127;
  int r  = (t >> 7) % 116;
  int b  = t / (116 * 128);
  int y, x;
  if (r < 30)      { y = 0;      x = r; }
  else if (r < 60) { y = 29;     x = r - 30; }
  else if (r < 88) { y = r - 59; x = 0; }
  else             { y = r - 87; x = 29; }
  size_t off = (((size_t)b * 30 + y) * 30 + x) * 1024 + (size_t)c8 * 8;
  *(uint4*)(h1p + off) = uint4{0, 0, 0, 0};
}

// ---------------- k_cast_pool: x NCHW fp32 -> xT [P][1024] bf16, + 4x4 avgpool (fp32) ----------------
__global__ __launch_bounds__(256) void k_cast_pool(
    const float* __restrict__ x, bf16* __restrict__ xT, float* __restrict__ pooled)
{
  const int pt = blockIdx.x, ct = blockIdx.y, b = blockIdx.z;   // 7,16,32
  __shared__ float tile[64 * 116];
  const int tid = threadIdx.x;
  const float* src = x + ((size_t)(b * 1024 + ct * 64)) * 784 + pt * 112;
  #pragma unroll
  for (int it = 0; it < 7; it++) {
    unsigned f = tid + it * 256;            // 0..1791 : 64 rows x 28 float4
    unsigned ci = f / 28, j = f % 28;
    float4 v = *(const float4*)(src + (size_t)ci * 784 + j * 4);
    *(float4*)(tile + ci * 116 + j * 4) = v;
  }
  __syncthreads();
  bf16* dst = xT + ((size_t)(b * 784 + pt * 112)) * 1024 + ct * 64;
  for (int s = tid; s < 896; s += 256) {
    int j = s >> 3, c8 = s & 7;
    bf16x8 tmp;
    #pragma unroll
    for (int e = 0; e < 8; e++) tmp[e] = (bf16)tile[(c8 * 8 + e) * 116 + j];
    *(bf16x8*)(dst + (size_t)j * 1024 + c8 * 8) = tmp;
  }
  for (int s = tid; s < 448; s += 256) {
    int c = s / 7, ox = s % 7;
    float acc = 0.f;
    #pragma unroll
    for (int yy = 0; yy < 4; yy++)
      #pragma unroll
      for (int xx = 0; xx < 4; xx++)
        acc += tile[c * 116 + yy * 28 + ox * 4 + xx];
    pooled[((size_t)(b * 1024 + ct * 64 + c)) * 49 + pt * 7 + ox] = acc * (1.0f / 16.0f);
  }
}

// ---------------- k_mask: logits, mask7, dilation, counts (all fp32) ----------------
__global__ __launch_bounds__(128) void k_mask(
    const float* __restrict__ pooled, const float* __restrict__ mkw, const float* __restrict__ mkb,
    float* __restrict__ mask7, unsigned* __restrict__ cnts)
{
  const int b = blockIdx.x, tid = threadIdx.x;
  __shared__ float l0s[49], l1s[49];
  __shared__ unsigned char m7[49];
  const int j = tid >> 6, p = tid & 63;
  if (p < 49) {
    const float* pb = pooled + (size_t)b * 1024 * 49 + p;
    const float* wr = mkw + j * 1024;
    float acc = 0.f;
    #pragma unroll 8
    for (int c = 0; c < 1024; c++) acc += pb[(size_t)c * 49] * wr[c];
    acc += mkb[j];
    if (j == 0) l0s[p] = acc; else l1s[p] = acc;
  }
  __syncthreads();
  if (tid < 49) {
    unsigned char m = (l0s[tid] >= l1s[tid]) ? 1 : 0;
    m7[tid] = m;
    mask7[b * 49 + tid] = (float)m;
  }
  __syncthreads();
  if (tid < 64) {
    unsigned long long bal = __ballot((tid < 49) && m7[tid]);
    if (tid == 0) atomicAdd(&cnts[0], (unsigned)__popcll(bal));
  }
  int cnt = 0;
  for (int p2 = tid; p2 < 784; p2 += 128) {
    int y = p2 / 28, x = p2 % 28;
    int cy0 = (y == 0) ? 0 : (y - 1) >> 2, cy1 = (y == 27) ? 6 : (y + 1) >> 2;
    int cx0 = (x == 0) ? 0 : (x - 1) >> 2, cx1 = (x == 27) ? 6 : (x + 1) >> 2;
    int d = 0;
    for (int cy = cy0; cy <= cy1; cy++)
      for (int cx = cx0; cx <= cx1; cx++) d |= m7[cy * 7 + cx];
    cnt += d;
  }
  cnt += __shfl_xor(cnt, 1);  cnt += __shfl_xor(cnt, 2);  cnt += __shfl_xor(cnt, 4);
  cnt += __shfl_xor(cnt, 8);  cnt += __shfl_xor(cnt, 16); cnt += __shfl_xor(cnt, 32);
  __shared__ int wsum[2];
  if ((tid & 63) == 0) wsum[tid >> 6] = cnt;
  __syncthreads();
  if (tid == 0) atomicAdd(&cnts[1], (unsigned)(wsum[0] + wsum[1]));
}

// ---------------- k_fin: scalar outputs ----------------
__global__ void k_fin(const unsigned* __restrict__ cnts, float* __restrict__ tail)
{
  if (threadIdx.x == 0 && blockIdx.x == 0) {
    float sp = (float)cnts[0] / 1568.0f;
    float sd = (float)cnts[1] / 25088.0f;
    const float c1 = 1048576.0f, c2 = 589824.0f, c3 = 1048576.0f, mf = 200704.0f;
    float dense  = mf + (c1 + c2 + c3) * 784.0f;
    float sparse = mf + c1 * 784.0f * sd + (c2 + c3) * 784.0f * sp;
    tail[0] = sp; tail[1] = sd; tail[2] = sparse / dense; tail[3] = sparse;
  }
}

// ---------------- k_gemm: D[m][n] = sum_k A[m][k]*B[n][k], 128x128 tile, BK=64 ----------------
// Rows (q*4+r) of C/D run along the CONTIGUOUS output dim.
// MODE 0 (conv_a): A=wa_bf (m=co), B=xT (n=pixel) -> h1p bf16 NHWC padded, BN_a+ReLU, bf16x4 stores
// MODE 1 (conv_c): A=h2T (m=pixel, s2-scaled in-flight), B=wc_bf (n=co)
//                  -> out fp32 NCHW, BN_c+mask+residual+ReLU, float4 ld/st
template<int MODE>
__global__ __launch_bounds__(256) void k_gemm(
    const bf16* __restrict__ Aop, const bf16* __restrict__ Bop, void* __restrict__ outp,
    const float* __restrict__ bn6, const float* __restrict__ xres,
    const float* __restrict__ mask7, const float* __restrict__ s2)
{
  const int mt = (MODE == 0) ? blockIdx.x : blockIdx.y;
  const int nt = (MODE == 0) ? blockIdx.y : blockIdx.x;
  __shared__ bf16 ldsA[8192];   // 128 x 64, xor-swizzled chunks
  __shared__ bf16 ldsB[8192];
  __shared__ float ldsS[MODE ? 2048 : 4];
  const int tid = threadIdx.x, lane = tid & 63, w = tid >> 6;
  const int wm = w & 1, wn = w >> 1;
  const int li = lane & 15, q = lane >> 4;

  int b0 = 0, soff[4];
  if constexpr (MODE == 1) {
    b0 = (mt * 128) / 784;
    int b1 = (mt * 128 + 127) / 784;
    for (int i = tid; i < 512; i += 256) {
      int bs = i >> 7, f4 = i & 127;
      *(f32x4*)(ldsS + i * 4) = *(const f32x4*)(s2 + (size_t)(bs ? b1 : b0) * 1024 + f4 * 4);
    }
    #pragma unroll
    for (int m = 0; m < 4; m++)
      soff[m] = (((mt * 128 + wm * 64 + m * 16) / 784) - b0) * 1024;  // 16 | 784: no straddle
  }

  const bf16* Ab = Aop + (size_t)mt * 128 * 1024;
  const bf16* Bb = Bop + (size_t)nt * 128 * 1024;
  const bf16* ga[4]; const bf16* gb[4];
  #pragma unroll
  for (int j = 0; j < 4; j++) {
    int c = w * 256 + j * 64 + lane;
    int row = c >> 3, k8 = (c & 7) ^ (row & 7);
    ga[j] = Ab + (size_t)row * 1024 + k8 * 8;
    gb[j] = Bb + (size_t)row * 1024 + k8 * 8;
  }
  const int lb = li * 128 + ((q ^ (li & 7)) << 4);
  f32x4 acc[4][4] = {};

  for (int kt = 0; kt < 16; kt++) {
    #pragma unroll
    for (int j = 0; j < 4; j++) gload16(ga[j], (char*)ldsA + w * 4096 + j * 1024);
    #pragma unroll
    for (int j = 0; j < 4; j++) gload16(gb[j], (char*)ldsB + w * 4096 + j * 1024);
    #pragma unroll
    for (int j = 0; j < 4; j++) { ga[j] += 64; gb[j] += 64; }
    __syncthreads();
    #pragma unroll
    for (int ks = 0; ks < 2; ks++) {
      bf16x8 af[4], bfr[4];
      #pragma unroll
      for (int m = 0; m < 4; m++)
        af[m] = *(const bf16x8*)((const char*)ldsA + wm * 8192 + m * 2048 + (lb ^ (ks * 64)));
      #pragma unroll
      for (int n = 0; n < 4; n++)
        bfr[n] = *(const bf16x8*)((const char*)ldsB + wn * 8192 + n * 2048 + (lb ^ (ks * 64)));
      if constexpr (MODE == 1) {
        #pragma unroll
        for (int m = 0; m < 4; m++) {
          const float* sp = ldsS + soff[m] + kt * 64 + ks * 32 + q * 8;
          f32x4 s0 = *(const f32x4*)sp;
          f32x4 s1 = *(const f32x4*)(sp + 4);
          #pragma unroll
          for (int j = 0; j < 4; j++) {
            af[m][j]     = (bf16)((float)af[m][j]     * s0[j]);
            af[m][4 + j] = (bf16)((float)af[m][4 + j] * s1[j]);
          }
        }
      }
      #pragma unroll
      for (int m = 0; m < 4; m++)
        #pragma unroll
        for (int n = 0; n < 4; n++)
          acc[m][n] = __builtin_amdgcn_mfma_f32_16x16x32_bf16(af[m], bfr[n], acc[m][n], 0, 0, 0);
    }
    __syncthreads();
  }

  if constexpr (MODE == 0) {
    // rows = co (contiguous in h1p), cols = pixel
    bf16* h1p = (bf16*)outp;
    const int co0 = mt * 128 + wm * 64 + q * 4;
    f32x4 sv[4], ov[4];
    #pragma unroll
    for (int m = 0; m < 4; m++) {
      sv[m] = *(const f32x4*)(bn6 + co0 + m * 16);
      ov[m] = *(const f32x4*)(bn6 + 1024 + co0 + m * 16);
    }
    #pragma unroll
    for (int n = 0; n < 4; n++) {
      unsigned p = nt * 128 + wn * 64 + n * 16 + li;
      unsigned b = p / 784u, rem = p % 784u;
      unsigned y = rem / 28u, xx = rem % 28u;
      bf16* dst = h1p + (((size_t)b * 30 + y + 1) * 30 + xx + 1) * 1024 + co0;
      #pragma unroll
      for (int m = 0; m < 4; m++) {
        bf16x4 pk;
        #pragma unroll
        for (int r = 0; r < 4; r++)
          pk[r] = (bf16)fmaxf(acc[m][n][r] * sv[m][r] + ov[m][r], 0.f);
        *(bf16x4*)(dst + m * 16) = pk;
      }
    }
  } else {
    // rows = pixel (contiguous in NCHW), cols = co
    float* dst = (float*)outp;
    const int p0 = mt * 128 + wm * 64 + q * 4;
    int bM[4]; unsigned hwM[4]; float mvv[4];
    #pragma unroll
    for (int m = 0; m < 4; m++) {
      int pm = p0 + m * 16;
      int b = pm / 784; unsigned hw = pm - b * 784;
      bM[m] = b; hwM[m] = hw;
      unsigned y = hw / 28u, xx = hw % 28u;
      mvv[m] = mask7[b * 49 + (y >> 2) * 7 + (xx >> 2)];
    }
    #pragma unroll
    for (int n = 0; n < 4; n++) {
      int co = nt * 128 + wn * 64 + n * 16 + li;
      float s = bn6[4096 + co], o = bn6[5120 + co];
      #pragma unroll
      for (int m = 0; m < 4; m++) {
        size_t base = ((size_t)(bM[m] * 1024 + co)) * 784 + hwM[m];
        f32x4 xv = *(const f32x4*)(xres + base);
        f32x4 rv;
        #pragma unroll
        for (int r = 0; r < 4; r++) {
          float v = acc[m][n][r] * s + o;
          rv[r] = fmaxf(v * mvv[m] + xv[r], 0.f);
        }
        *(f32x4*)(dst + base) = rv;
      }
    }
  }
}

// ---------------- k_conv_b: grouped 3x3 + BN + ReLU + SE partial sums (atomics) ----------------
// grid (32 b, 16 g, 7 yt): each block computes 4 output rows (112 pixels) for 64 co.
__global__ __launch_bounds__(256) void k_conv_b(
    const bf16* __restrict__ h1p, const bf16* __restrict__ wb_bf,
    bf16* __restrict__ h2T, float* __restrict__ sums, const float* __restrict__ bn6)
{
  const int b = blockIdx.x, g = blockIdx.y, yt = blockIdx.z;
  __shared__ bf16 ldsI[184 * 64];     // 23552 B, xor-swizzled [pos][ci]; 180 used
  const int tid = threadIdx.x, lane = tid & 63, w = tid >> 6;
  const int li = lane & 15, q = lane >> 4;

  // weight frags (A operand): lane co = g*64 + w*16 + li; k(ci) = cs*32 + q*8 + j
  bf16x8 wreg[9][2];
  #pragma unroll
  for (int kk = 0; kk < 9; kk++)
    #pragma unroll
    for (int cs = 0; cs < 2; cs++)
      wreg[kk][cs] = *(const bf16x8*)(wb_bf +
          (((size_t)(g * 9 + kk) * 64) + w * 16 + li) * 64 + cs * 32 + q * 8);

  // stage 180 positions (6 padded rows of 30) starting at padded row 4*yt
  const bf16* iBase = h1p + (size_t)b * 921600 + (size_t)(4 * yt) * 30 * 1024 + g * 64;
  #pragma unroll
  for (int t = 0; t < 6; t++) {
    int j = w + t * 4;
    if (j < 23 && (j < 22 || lane < 32)) {
      int c = j * 64 + lane;
      int pos = c >> 3, ci8 = (c & 7) ^ (pos & 7);
      gload16(iBase + (size_t)pos * 1024 + ci8 * 8, (char*)ldsI + j * 1024);
    }
  }

  int pos0[7];
  #pragma unroll
  for (int mtt = 0; mtt < 7; mtt++) {
    int n = mtt * 16 + li;
    pos0[mtt] = (n / 28) * 30 + (n % 28);
  }
  __syncthreads();

  f32x4 acc[7] = {};
  #pragma unroll
  for (int kk = 0; kk < 9; kk++) {
    const int shift = (kk / 3) * 30 + (kk % 3);
    #pragma unroll
    for (int cs = 0; cs < 2; cs++) {
      #pragma unroll
      for (int mtt = 0; mtt < 7; mtt++) {
        int pos = pos0[mtt] + shift;
        int off = pos * 128 + ((((cs << 2) + q) ^ (pos & 7)) << 4);
        bf16x8 ifr = *(const bf16x8*)((const char*)ldsI + off);
        acc[mtt] = __builtin_amdgcn_mfma_f32_16x16x32_bf16(wreg[kk][cs], ifr, acc[mtt], 0, 0, 0);
      }
    }
  }

  // epilogue: rows = co (q*4+r), cols = pixel (li)
  const int co4 = g * 64 + w * 16 + q * 4;
  f32x4 sv = *(const f32x4*)(bn6 + 2048 + co4);
  f32x4 ov = *(const f32x4*)(bn6 + 3072 + co4);
  f32x4 csum = {0.f, 0.f, 0.f, 0.f};
  #pragma unroll
  for (int mtt = 0; mtt < 7; mtt++) {
    int pl = yt * 112 + mtt * 16 + li;
    bf16x4 pk;
    #pragma unroll
    for (int r = 0; r < 4; r++) {
      float v = fmaxf(acc[mtt][r] * sv[r] + ov[r], 0.f);
      csum[r] += v;
      pk[r] = (bf16)v;
    }
    *(bf16x4*)(h2T + ((size_t)b * 784 + pl) * 1024 + co4) = pk;
  }
  #pragma unroll
  for (int d = 1; d < 16; d <<= 1) {
    #pragma unroll
    for (int r = 0; r < 4; r++) csum[r] += __shfl_xor(csum[r], d);
  }
  if (li == 0) {
    #pragma unroll
    for (int r = 0; r < 4; r++) atomicAdd(&sums[b * 1024 + co4 + r], csum[r]);
  }
}

// ---------------- k_se: squeeze-excite MLP (fp32) ----------------
__global__ __launch_bounds__(256) void k_se(
    const float* __restrict__ sums, const float* __restrict__ sw1, const float* __restrict__ sb1,
    const float* __restrict__ sw2, const float* __restrict__ sb2, float* __restrict__ s2)
{
  const int b = blockIdx.x, tid = threadIdx.x;
  __shared__ float mean[1024];
  __shared__ float s1[256];
  for (int i = tid; i < 1024; i += 256) mean[i] = sums[b * 1024 + i] * (1.0f / 784.0f);
  __syncthreads();
  {
    float acc = sb1[tid];
    const float4* wr = (const float4*)(sw1 + (size_t)tid * 1024);
    #pragma unroll 4
    for (int c4 = 0; c4 < 256; c4++) {
      float4 wv = wr[c4];
      acc += wv.x * mean[c4 * 4] + wv.y * mean[c4 * 4 + 1] + wv.z * mean[c4 * 4 + 2] + wv.w * mean[c4 * 4 + 3];
    }
    s1[tid] = fmaxf(acc, 0.f);
  }
  __syncthreads();
  for (int co = tid; co < 1024; co += 256) {
    float acc = sb2[co];
    const float4* wr = (const float4*)(sw2 + (size_t)co * 256);
    #pragma unroll 4
    for (int q4 = 0; q4 < 64; q4++) {
      float4 wv = wr[q4];
      acc += wv.x * s1[q4 * 4] + wv.y * s1[q4 * 4 + 1] + wv.z * s1[q4 * 4 + 2] + wv.w * s1[q4 * 4 + 3];
    }
    s2[b * 1024 + co] = 1.0f / (1.0f + __expf(-acc));
  }
}

// ---------------- launch ----------------
extern "C" void kernel_launch(void* const* d_in, const int* in_sizes, int n_in,
                              void* d_out, int out_size, void* d_ws, size_t ws_size,
                              hipStream_t stream)
{
  const float* x   = (const float*)d_in[0];
  const float* wa  = (const float*)d_in[2];
  const float* ga  = (const float*)d_in[3];
  const float* ba  = (const float*)d_in[4];
  const float* ma  = (const float*)d_in[5];
  const float* va  = (const float*)d_in[6];
  const float* wb  = (const float*)d_in[7];
  const float* gb  = (const float*)d_in[8];
  const float* bb  = (const float*)d_in[9];
  const float* mb  = (const float*)d_in[10];
  const float* vb  = (const float*)d_in[11];
  const float* sw1 = (const float*)d_in[12];
  const float* sb1 = (const float*)d_in[13];
  const float* sw2 = (const float*)d_in[14];
  const float* sb2 = (const float*)d_in[15];
  const float* wc  = (const float*)d_in[16];
  const float* gc  = (const float*)d_in[17];
  const float* bc  = (const float*)d_in[18];
  const float* mc  = (const float*)d_in[19];
  const float* vc  = (const float*)d_in[20];
  const float* mkw = (const float*)d_in[21];
  const float* mkb = (const float*)d_in[22];

  char* ws = (char*)d_ws;
  bf16*  xT     = (bf16*)(ws + 0);              // 51,380,224 B (reused as h2T)
  bf16*  h1p    = (bf16*)(ws + 51380224);       // 58,982,400 B + slack
  bf16*  wa_bf  = (bf16*)(ws + 110428160);      // 2,097,152
  bf16*  wc_bf  = (bf16*)(ws + 112525312);      // 2,097,152
  float* pooled = (float*)(ws + 114622464);     // 6,422,528 (reused as wb_bf after k_mask)
  bf16*  wb_bf  = (bf16*)(ws + 114622464);      // 1,179,648 (alias: written after pooled is consumed)
  float* mask7  = (float*)(ws + 121044992);     // 8,192
  float* sums   = (float*)(ws + 121053184);     // 131,072
  float* s2     = (float*)(ws + 121184256);     // 131,072
  float* bn6    = (float*)(ws + 121315328);     // 24,576
  unsigned* cnts = (unsigned*)(ws + 121339904); // 8

  float* out = (float*)d_out;

  k_prep<<<1024, 256, 0, stream>>>(wa, wc, ga, ba, ma, va, gb, bb, mb, vb, gc, bc, mc, vc,
                                   wa_bf, wc_bf, bn6, sums, cnts);
  k_ring<<<1856, 256, 0, stream>>>(h1p);
  k_cast_pool<<<dim3(7, 16, 32), 256, 0, stream>>>(x, xT, pooled);
  k_mask<<<32, 128, 0, stream>>>(pooled, mkw, mkb, mask7, cnts);
  k_fin<<<1, 64, 0, stream>>>(cnts, out + 25690112);
  k_prepw<<<2304, 256, 0, stream>>>(wb, wb_bf);   // after k_mask: aliases pooled
  k_gemm<0><<<dim3(8, 196), 256, 0, stream>>>(wa_bf, xT, h1p, bn6, nullptr, nullptr, nullptr);
  k_conv_b<<<dim3(32, 16, 7), 256, 0, stream>>>(h1p, wb_bf, xT /*h2T*/, sums, bn6);
  k_se<<<32, 256, 0, stream>>>(sums, sw1, sb1, sw2, sb2, s2);
  k_gemm<1><<<dim3(8, 196), 256, 0, stream>>>(xT /*h2T*/, wc_bf, out, bn6, x, mask7, s2);
}

// Round 4
// 502.033 us; speedup vs baseline: 1.3624x; 1.2307x over previous
//
#include <hip/hip_runtime.h>

typedef __bf16 bf16;
typedef __bf16 bf16x8 __attribute__((ext_vector_type(8)));
typedef __bf16 bf16x4 __attribute__((ext_vector_type(4)));
typedef float  f32x4  __attribute__((ext_vector_type(4)));

#define EPSBN 1e-5f

// ---------------- async global->LDS (16B per lane) ----------------
__device__ __forceinline__ void gload16(const void* gp, void* lp) {
  __builtin_amdgcn_global_load_lds(
      (__attribute__((address_space(1))) void*)(unsigned long long)gp,
      (__attribute__((address_space(3))) void*)(unsigned)(unsigned long long)lp,
      16, 0, 0);
}

// ---------------- k_init: merged prep (wa/wc cast + BN fold + zero) | prepw | ring ----------------
__global__ __launch_bounds__(256) void k_init(
    const float* __restrict__ wa, const float* __restrict__ wc, const float* __restrict__ wb,
    const float* __restrict__ ga, const float* __restrict__ ba, const float* __restrict__ ma, const float* __restrict__ va,
    const float* __restrict__ gb, const float* __restrict__ bb, const float* __restrict__ mb, const float* __restrict__ vb,
    const float* __restrict__ gc, const float* __restrict__ bc, const float* __restrict__ mc, const float* __restrict__ vc,
    bf16* __restrict__ wa_bf, bf16* __restrict__ wc_bf, bf16* __restrict__ wb_bf,
    float* __restrict__ bn6, float* __restrict__ sums, unsigned* __restrict__ cnts,
    bf16* __restrict__ h1p)
{
  const int bid = blockIdx.x, tid = threadIdx.x;
  if (bid < 1024) {
    // ---- prep: cast 1x1 weights, fold BN, zero sums/cnts
    unsigned i = bid * 256 + tid;
    unsigned e = i * 4;
    float4 a = *(const float4*)(wa + e);
    bf16x4 av; av[0]=(bf16)a.x; av[1]=(bf16)a.y; av[2]=(bf16)a.z; av[3]=(bf16)a.w;
    *(bf16x4*)(wa_bf + e) = av;
    float4 c = *(const float4*)(wc + e);
    bf16x4 cv; cv[0]=(bf16)c.x; cv[1]=(bf16)c.y; cv[2]=(bf16)c.z; cv[3]=(bf16)c.w;
    *(bf16x4*)(wc_bf + e) = cv;
    if (i < 1024) {
      float s;
      s = ga[i] / sqrtf(va[i] + EPSBN); bn6[i]        = s; bn6[1024 + i] = ba[i] - ma[i] * s;
      s = gb[i] / sqrtf(vb[i] + EPSBN); bn6[2048 + i] = s; bn6[3072 + i] = bb[i] - mb[i] * s;
      s = gc[i] / sqrtf(vc[i] + EPSBN); bn6[4096 + i] = s; bn6[5120 + i] = bc[i] - mc[i] * s;
    }
    if (i < 32768) sums[i] = 0.f;
    if (i == 0) { cnts[0] = 0u; cnts[1] = 0u; }
  } else if (bid < 3328) {
    // ---- prepw: wb fp32 [co][ci][3][3] -> bf16 frag layout [g*9+kk][co%64][ci]
    int t = (bid - 1024) * 256 + tid;          // 589824
    int ci = t & 63;
    int u  = t >> 6;
    int cl = u & 63;
    int gk = u >> 6;
    int g  = gk / 9, kk = gk - g * 9;
    wb_bf[t] = (bf16)wb[(((size_t)(g * 64 + cl) * 64) + ci) * 9 + kk];
  } else {
    // ---- ring: zero the 1-pixel pad ring of h1p [32][30][30][1024]
    int t = (bid - 3328) * 256 + tid;          // 475136 = 32*116*128
    int c8 = t & 127;
    int r  = (t >> 7) % 116;
    int b  = t / (116 * 128);
    int y, x;
    if (r < 30)      { y = 0;      x = r; }
    else if (r < 60) { y = 29;     x = r - 30; }
    else if (r < 88) { y = r - 59; x = 0; }
    else             { y = r - 87; x = 29; }
    size_t off = (((size_t)b * 30 + y) * 30 + x) * 1024 + (size_t)c8 * 8;
    *(uint4*)(h1p + off) = uint4{0, 0, 0, 0};
  }
}

// ---------------- k_cast_pool: x NCHW fp32 -> xT [P][1024] bf16, + 4x4 avgpool -> pooledb [b][49][1024] bf16 ----------------
__global__ __launch_bounds__(256) void k_cast_pool(
    const float* __restrict__ x, bf16* __restrict__ xT, bf16* __restrict__ pooledb)
{
  const int pt = blockIdx.x, ct = blockIdx.y, b = blockIdx.z;   // 7,16,32
  __shared__ float tile[64 * 116];
  const int tid = threadIdx.x;
  const float* src = x + ((size_t)(b * 1024 + ct * 64)) * 784 + pt * 112;
  #pragma unroll
  for (int it = 0; it < 7; it++) {
    unsigned f = tid + it * 256;            // 0..1791 : 64 rows x 28 float4
    unsigned ci = f / 28, j = f % 28;
    float4 v = *(const float4*)(src + (size_t)ci * 784 + j * 4);
    *(float4*)(tile + ci * 116 + j * 4) = v;
  }
  __syncthreads();
  bf16* dst = xT + ((size_t)(b * 784 + pt * 112)) * 1024 + ct * 64;
  for (int s = tid; s < 896; s += 256) {
    int j = s >> 3, c8 = s & 7;
    bf16x8 tmp;
    #pragma unroll
    for (int e = 0; e < 8; e++) tmp[e] = (bf16)tile[(c8 * 8 + e) * 116 + j];
    *(bf16x8*)(dst + (size_t)j * 1024 + c8 * 8) = tmp;
  }
  for (int s = tid; s < 448; s += 256) {
    int c = s / 7, ox = s % 7;
    float acc = 0.f;
    #pragma unroll
    for (int yy = 0; yy < 4; yy++)
      #pragma unroll
      for (int xx = 0; xx < 4; xx++)
        acc += tile[c * 116 + yy * 28 + ox * 4 + xx];
    pooledb[((size_t)b * 49 + pt * 7 + ox) * 1024 + ct * 64 + c] = (bf16)(acc * (1.0f / 16.0f));
  }
}

// ---------------- k_mask: logits (coalesced bf16 dots), mask7, dilation, counts ----------------
__global__ __launch_bounds__(256) void k_mask(
    const bf16* __restrict__ pooledb, const float* __restrict__ mkw, const float* __restrict__ mkb,
    float* __restrict__ mask7, unsigned* __restrict__ cnts)
{
  const int b = blockIdx.x, tid = threadIdx.x;
  const int lane = tid & 63, w = tid >> 6;
  __shared__ float l0s[49], l1s[49];
  __shared__ unsigned char m7[56];
  // hoist per-lane weights (16 channels each)
  float w0r[16], w1r[16];
  #pragma unroll
  for (int i = 0; i < 4; i++) {
    *(f32x4*)(w0r + i * 4) = *(const f32x4*)(mkw + lane * 16 + i * 4);
    *(f32x4*)(w1r + i * 4) = *(const f32x4*)(mkw + 1024 + lane * 16 + i * 4);
  }
  const float mkb0 = mkb[0], mkb1 = mkb[1];
  for (int p = w; p < 49; p += 4) {
    const bf16* pp = pooledb + ((size_t)b * 49 + p) * 1024 + lane * 16;
    bf16x8 h0 = *(const bf16x8*)pp;
    bf16x8 h1 = *(const bf16x8*)(pp + 8);
    float a0 = 0.f, a1 = 0.f;
    #pragma unroll
    for (int e = 0; e < 8; e++) {
      float v0 = (float)h0[e], v1 = (float)h1[e];
      a0 += v0 * w0r[e] + v1 * w0r[8 + e];
      a1 += v0 * w1r[e] + v1 * w1r[8 + e];
    }
    #pragma unroll
    for (int d = 1; d < 64; d <<= 1) { a0 += __shfl_xor(a0, d); a1 += __shfl_xor(a1, d); }
    if (lane == 0) { l0s[p] = a0 + mkb0; l1s[p] = a1 + mkb1; }
  }
  __syncthreads();
  if (tid < 49) {
    unsigned char m = (l0s[tid] >= l1s[tid]) ? 1 : 0;
    m7[tid] = m;
    mask7[b * 49 + tid] = (float)m;
  }
  __syncthreads();
  if (tid < 64) {
    unsigned long long bal = __ballot((tid < 49) && m7[tid]);
    if (tid == 0) atomicAdd(&cnts[0], (unsigned)__popcll(bal));
  }
  int cnt = 0;
  for (int p2 = tid; p2 < 784; p2 += 256) {
    int y = p2 / 28, x = p2 % 28;
    int cy0 = (y == 0) ? 0 : (y - 1) >> 2, cy1 = (y == 27) ? 6 : (y + 1) >> 2;
    int cx0 = (x == 0) ? 0 : (x - 1) >> 2, cx1 = (x == 27) ? 6 : (x + 1) >> 2;
    int d = 0;
    for (int cy = cy0; cy <= cy1; cy++)
      for (int cx = cx0; cx <= cx1; cx++) d |= m7[cy * 7 + cx];
    cnt += d;
  }
  #pragma unroll
  for (int d = 1; d < 64; d <<= 1) cnt += __shfl_xor(cnt, d);
  __shared__ int wsum[4];
  if (lane == 0) wsum[w] = cnt;
  __syncthreads();
  if (tid == 0) atomicAdd(&cnts[1], (unsigned)(wsum[0] + wsum[1] + wsum[2] + wsum[3]));
}

// ---------------- k_fin: scalar outputs ----------------
__global__ void k_fin(const unsigned* __restrict__ cnts, float* __restrict__ tail)
{
  if (threadIdx.x == 0 && blockIdx.x == 0) {
    float sp = (float)cnts[0] / 1568.0f;
    float sd = (float)cnts[1] / 25088.0f;
    const float c1 = 1048576.0f, c2 = 589824.0f, c3 = 1048576.0f, mf = 200704.0f;
    float dense  = mf + (c1 + c2 + c3) * 784.0f;
    float sparse = mf + c1 * 784.0f * sd + (c2 + c3) * 784.0f * sp;
    tail[0] = sp; tail[1] = sd; tail[2] = sparse / dense; tail[3] = sparse;
  }
}

// ---------------- k_gemm: D[m][n] = sum_k A[m][k]*B[n][k], 128x128 tile, BK=64 ----------------
// 1D grid 1568, 64-block supertiles (8 pix-tiles x 8 co-tiles) for L2/L3 locality.
// MODE 0 (conv_a): A=wa_bf (m=co), B=xT (n=pixel) -> h1p bf16 NHWC padded, BN_a+ReLU
// MODE 1 (conv_c): A=h2Ts (m=pixel, pre-scaled), B=wc_bf (n=co) -> out fp32 NCHW, BN_c+mask+res+ReLU
template<int MODE>
__global__ __launch_bounds__(256) void k_gemm(
    const bf16* __restrict__ Aop, const bf16* __restrict__ Bop, void* __restrict__ outp,
    const float* __restrict__ bn6, const float* __restrict__ xres,
    const float* __restrict__ mask7)
{
  int id = blockIdx.x, pixt, cot;
  if (id < 1536) { pixt = (id >> 6) * 8 + (id & 7); cot = (id >> 3) & 7; }
  else { int wi = id - 1536; pixt = 192 + (wi & 3); cot = wi >> 2; }
  const int mt = (MODE == 0) ? cot : pixt;
  const int nt = (MODE == 0) ? pixt : cot;

  __shared__ bf16 ldsA[8192];   // 128 x 64, xor-swizzled chunks
  __shared__ bf16 ldsB[8192];
  const int tid = threadIdx.x, lane = tid & 63, w = tid >> 6;
  const int wm = w & 1, wn = w >> 1;
  const int li = lane & 15, q = lane >> 4;

  const bf16* Ab = Aop + (size_t)mt * 128 * 1024;
  const bf16* Bb = Bop + (size_t)nt * 128 * 1024;
  const bf16* ga[4]; const bf16* gb[4];
  #pragma unroll
  for (int j = 0; j < 4; j++) {
    int c = w * 256 + j * 64 + lane;
    int row = c >> 3, k8 = (c & 7) ^ (row & 7);
    ga[j] = Ab + (size_t)row * 1024 + k8 * 8;
    gb[j] = Bb + (size_t)row * 1024 + k8 * 8;
  }
  const int lb = li * 128 + ((q ^ (li & 7)) << 4);
  f32x4 acc[4][4] = {};

  for (int kt = 0; kt < 16; kt++) {
    #pragma unroll
    for (int j = 0; j < 4; j++) gload16(ga[j], (char*)ldsA + w * 4096 + j * 1024);
    #pragma unroll
    for (int j = 0; j < 4; j++) gload16(gb[j], (char*)ldsB + w * 4096 + j * 1024);
    #pragma unroll
    for (int j = 0; j < 4; j++) { ga[j] += 64; gb[j] += 64; }
    __syncthreads();
    #pragma unroll
    for (int ks = 0; ks < 2; ks++) {
      bf16x8 af[4], bfr[4];
      #pragma unroll
      for (int m = 0; m < 4; m++)
        af[m] = *(const bf16x8*)((const char*)ldsA + wm * 8192 + m * 2048 + (lb ^ (ks * 64)));
      #pragma unroll
      for (int n = 0; n < 4; n++)
        bfr[n] = *(const bf16x8*)((const char*)ldsB + wn * 8192 + n * 2048 + (lb ^ (ks * 64)));
      #pragma unroll
      for (int m = 0; m < 4; m++)
        #pragma unroll
        for (int n = 0; n < 4; n++)
          acc[m][n] = __builtin_amdgcn_mfma_f32_16x16x32_bf16(af[m], bfr[n], acc[m][n], 0, 0, 0);
    }
    __syncthreads();
  }

  if constexpr (MODE == 0) {
    // rows = co (contiguous in h1p), cols = pixel
    bf16* h1p = (bf16*)outp;
    const int co0 = mt * 128 + wm * 64 + q * 4;
    f32x4 sv[4], ov[4];
    #pragma unroll
    for (int m = 0; m < 4; m++) {
      sv[m] = *(const f32x4*)(bn6 + co0 + m * 16);
      ov[m] = *(const f32x4*)(bn6 + 1024 + co0 + m * 16);
    }
    #pragma unroll
    for (int n = 0; n < 4; n++) {
      unsigned p = nt * 128 + wn * 64 + n * 16 + li;
      unsigned b = p / 784u, rem = p % 784u;
      unsigned y = rem / 28u, xx = rem % 28u;
      bf16* dst = h1p + (((size_t)b * 30 + y + 1) * 30 + xx + 1) * 1024 + co0;
      #pragma unroll
      for (int m = 0; m < 4; m++) {
        bf16x4 pk;
        #pragma unroll
        for (int r = 0; r < 4; r++)
          pk[r] = (bf16)fmaxf(acc[m][n][r] * sv[m][r] + ov[m][r], 0.f);
        *(bf16x4*)(dst + m * 16) = pk;
      }
    }
  } else {
    // rows = pixel (contiguous in NCHW), cols = co
    float* dst = (float*)outp;
    const int p0 = mt * 128 + wm * 64 + q * 4;
    int bM[4]; unsigned hwM[4]; float mvv[4];
    #pragma unroll
    for (int m = 0; m < 4; m++) {
      int pm = p0 + m * 16;
      int b = pm / 784; unsigned hw = pm - b * 784;
      bM[m] = b; hwM[m] = hw;
      unsigned y = hw / 28u, xx = hw % 28u;
      mvv[m] = mask7[b * 49 + (y >> 2) * 7 + (xx >> 2)];
    }
    #pragma unroll
    for (int n = 0; n < 4; n++) {
      int co = nt * 128 + wn * 64 + n * 16 + li;
      float s = bn6[4096 + co], o = bn6[5120 + co];
      #pragma unroll
      for (int m = 0; m < 4; m++) {
        size_t base = ((size_t)(bM[m] * 1024 + co)) * 784 + hwM[m];
        f32x4 xv = *(const f32x4*)(xres + base);
        f32x4 rv;
        #pragma unroll
        for (int r = 0; r < 4; r++) {
          float v = acc[m][n][r] * s + o;
          rv[r] = fmaxf(v * mvv[m] + xv[r], 0.f);
        }
        *(f32x4*)(dst + base) = rv;
      }
    }
  }
}

// ---------------- k_conv_b: grouped 3x3 + BN + ReLU + SE partial sums (atomics) ----------------
// grid (32 b, 16 g, 7 yt): each block computes 4 output rows (112 pixels) for 64 co.
__global__ __launch_bounds__(256) void k_conv_b(
    const bf16* __restrict__ h1p, const bf16* __restrict__ wb_bf,
    bf16* __restrict__ h2T, float* __restrict__ sums, const float* __restrict__ bn6)
{
  const int b = blockIdx.x, g = blockIdx.y, yt = blockIdx.z;
  __shared__ bf16 ldsI[184 * 64];     // 23552 B, xor-swizzled [pos][ci]; 180 used
  const int tid = threadIdx.x, lane = tid & 63, w = tid >> 6;
  const int li = lane & 15, q = lane >> 4;

  bf16x8 wreg[9][2];
  #pragma unroll
  for (int kk = 0; kk < 9; kk++)
    #pragma unroll
    for (int cs = 0; cs < 2; cs++)
      wreg[kk][cs] = *(const bf16x8*)(wb_bf +
          (((size_t)(g * 9 + kk) * 64) + w * 16 + li) * 64 + cs * 32 + q * 8);

  const bf16* iBase = h1p + (size_t)b * 921600 + (size_t)(4 * yt) * 30 * 1024 + g * 64;
  #pragma unroll
  for (int t = 0; t < 6; t++) {
    int j = w + t * 4;
    if (j < 23 && (j < 22 || lane < 32)) {
      int c = j * 64 + lane;
      int pos = c >> 3, ci8 = (c & 7) ^ (pos & 7);
      gload16(iBase + (size_t)pos * 1024 + ci8 * 8, (char*)ldsI + j * 1024);
    }
  }

  int pos0[7];
  #pragma unroll
  for (int mtt = 0; mtt < 7; mtt++) {
    int n = mtt * 16 + li;
    pos0[mtt] = (n / 28) * 30 + (n % 28);
  }
  __syncthreads();

  f32x4 acc[7] = {};
  #pragma unroll
  for (int kk = 0; kk < 9; kk++) {
    const int shift = (kk / 3) * 30 + (kk % 3);
    #pragma unroll
    for (int cs = 0; cs < 2; cs++) {
      #pragma unroll
      for (int mtt = 0; mtt < 7; mtt++) {
        int pos = pos0[mtt] + shift;
        int off = pos * 128 + ((((cs << 2) + q) ^ (pos & 7)) << 4);
        bf16x8 ifr = *(const bf16x8*)((const char*)ldsI + off);
        acc[mtt] = __builtin_amdgcn_mfma_f32_16x16x32_bf16(wreg[kk][cs], ifr, acc[mtt], 0, 0, 0);
      }
    }
  }

  const int co4 = g * 64 + w * 16 + q * 4;
  f32x4 sv = *(const f32x4*)(bn6 + 2048 + co4);
  f32x4 ov = *(const f32x4*)(bn6 + 3072 + co4);
  f32x4 csum = {0.f, 0.f, 0.f, 0.f};
  #pragma unroll
  for (int mtt = 0; mtt < 7; mtt++) {
    int pl = yt * 112 + mtt * 16 + li;
    bf16x4 pk;
    #pragma unroll
    for (int r = 0; r < 4; r++) {
      float v = fmaxf(acc[mtt][r] * sv[r] + ov[r], 0.f);
      csum[r] += v;
      pk[r] = (bf16)v;
    }
    *(bf16x4*)(h2T + ((size_t)b * 784 + pl) * 1024 + co4) = pk;
  }
  #pragma unroll
  for (int d = 1; d < 16; d <<= 1) {
    #pragma unroll
    for (int r = 0; r < 4; r++) csum[r] += __shfl_xor(csum[r], d);
  }
  if (li == 0) {
    #pragma unroll
    for (int r = 0; r < 4; r++) atomicAdd(&sums[b * 1024 + co4 + r], csum[r]);
  }
}

// ---------------- k_se1: s1[b][256] = relu(sw1 . mean + sb1) ----------------
__global__ __launch_bounds__(256) void k_se1(
    const float* __restrict__ sums, const float* __restrict__ sw1, const float* __restrict__ sb1,
    float* __restrict__ s1g)
{
  const int sqc = blockIdx.x, b = blockIdx.y, tid = threadIdx.x;   // 8, 32
  __shared__ float mean[1024];
  for (int i = tid; i < 1024; i += 256) mean[i] = sums[b * 1024 + i] * (1.0f / 784.0f);
  __syncthreads();
  const int row = sqc * 32 + (tid >> 3), part = tid & 7;
  const f32x4* wr = (const f32x4*)(sw1 + (size_t)row * 1024 + part * 128);
  const float* mr = mean + part * 128;
  float acc = 0.f;
  #pragma unroll 8
  for (int i = 0; i < 32; i++) {
    f32x4 wv = wr[i];
    acc += wv[0] * mr[i * 4] + wv[1] * mr[i * 4 + 1] + wv[2] * mr[i * 4 + 2] + wv[3] * mr[i * 4 + 3];
  }
  acc += __shfl_xor(acc, 1); acc += __shfl_xor(acc, 2); acc += __shfl_xor(acc, 4);
  if (part == 0) s1g[b * 256 + row] = fmaxf(acc + sb1[row], 0.f);
}

// ---------------- k_se2: s2[b][1024] = sigmoid(sw2 . s1 + sb2) ----------------
__global__ __launch_bounds__(256) void k_se2(
    const float* __restrict__ s1g, const float* __restrict__ sw2, const float* __restrict__ sb2,
    float* __restrict__ s2)
{
  const int coc = blockIdx.x, b = blockIdx.y, tid = threadIdx.x;   // 4, 32
  __shared__ float s1s[256];
  s1s[tid] = s1g[b * 256 + tid];
  __syncthreads();
  const int co = coc * 256 + tid;
  const f32x4* wr = (const f32x4*)(sw2 + (size_t)co * 256);
  float acc = sb2[co];
  #pragma unroll 8
  for (int i = 0; i < 64; i++) {
    f32x4 wv = wr[i];
    acc += wv[0] * s1s[i * 4] + wv[1] * s1s[i * 4 + 1] + wv[2] * s1s[i * 4 + 2] + wv[3] * s1s[i * 4 + 3];
  }
  s2[b * 1024 + co] = 1.0f / (1.0f + __expf(-acc));
}

// ---------------- k_scale: h2T *= s2 (in place) ----------------
__global__ __launch_bounds__(256) void k_scale(bf16* __restrict__ h2T, const float* __restrict__ s2)
{
  size_t idx = ((size_t)blockIdx.x * 256 + threadIdx.x) * 8;
  unsigned b = (unsigned)(idx / 802816u);         // 784*1024
  unsigned c = (unsigned)(idx & 1023u);
  const float* sp = s2 + b * 1024 + c;
  bf16x8 v = *(const bf16x8*)(h2T + idx);
  #pragma unroll
  for (int e = 0; e < 8; e++) v[e] = (bf16)((float)v[e] * sp[e]);
  *(bf16x8*)(h2T + idx) = v;
}

// ---------------- launch ----------------
extern "C" void kernel_launch(void* const* d_in, const int* in_sizes, int n_in,
                              void* d_out, int out_size, void* d_ws, size_t ws_size,
                              hipStream_t stream)
{
  const float* x   = (const float*)d_in[0];
  const float* wa  = (const float*)d_in[2];
  const float* ga  = (const float*)d_in[3];
  const float* ba  = (const float*)d_in[4];
  const float* ma  = (const float*)d_in[5];
  const float* va  = (const float*)d_in[6];
  const float* wb  = (const float*)d_in[7];
  const float* gb  = (const float*)d_in[8];
  const float* bb  = (const float*)d_in[9];
  const float* mb  = (const float*)d_in[10];
  const float* vb  = (const float*)d_in[11];
  const float* sw1 = (const float*)d_in[12];
  const float* sb1 = (const float*)d_in[13];
  const float* sw2 = (const float*)d_in[14];
  const float* sb2 = (const float*)d_in[15];
  const float* wc  = (const float*)d_in[16];
  const float* gc  = (const float*)d_in[17];
  const float* bc  = (const float*)d_in[18];
  const float* mc  = (const float*)d_in[19];
  const float* vc  = (const float*)d_in[20];
  const float* mkw = (const float*)d_in[21];
  const float* mkb = (const float*)d_in[22];

  char* ws = (char*)d_ws;
  bf16*  xT      = (bf16*)(ws + 0);              // 51,380,224 (reused as h2T)
  bf16*  h1p     = (bf16*)(ws + 51380224);       // 58,982,400
  bf16*  wa_bf   = (bf16*)(ws + 110362624);      // 2,097,152
  bf16*  wc_bf   = (bf16*)(ws + 112459776);      // 2,097,152
  bf16*  wb_bf   = (bf16*)(ws + 114556928);      // 1,179,648
  bf16*  pooledb = (bf16*)(ws + 115736576);      // 3,211,264
  float* mask7   = (float*)(ws + 118947840);     // 8,192
  float* sums    = (float*)(ws + 118956032);     // 131,072
  float* s1g     = (float*)(ws + 119087104);     // 32,768
  float* s2      = (float*)(ws + 119119872);     // 131,072
  float* bn6     = (float*)(ws + 119250944);     // 24,576
  unsigned* cnts = (unsigned*)(ws + 119275520);  // 8

  float* out = (float*)d_out;

  k_init<<<5184, 256, 0, stream>>>(wa, wc, wb, ga, ba, ma, va, gb, bb, mb, vb, gc, bc, mc, vc,
                                   wa_bf, wc_bf, wb_bf, bn6, sums, cnts, h1p);
  k_cast_pool<<<dim3(7, 16, 32), 256, 0, stream>>>(x, xT, pooledb);
  k_mask<<<32, 256, 0, stream>>>(pooledb, mkw, mkb, mask7, cnts);
  k_fin<<<1, 64, 0, stream>>>(cnts, out + 25690112);
  k_gemm<0><<<1568, 256, 0, stream>>>(wa_bf, xT, h1p, bn6, nullptr, nullptr);
  k_conv_b<<<dim3(32, 16, 7), 256, 0, stream>>>(h1p, wb_bf, xT /*h2T*/, sums, bn6);
  k_se1<<<dim3(8, 32), 256, 0, stream>>>(sums, sw1, sb1, s1g);
  k_se2<<<dim3(4, 32), 256, 0, stream>>>(s1g, sw2, sb2, s2);
  k_scale<<<12544, 256, 0, stream>>>(xT, s2);
  k_gemm<1><<<1568, 256, 0, stream>>>(xT /*h2T*/, wc_bf, out, bn6, x, mask7);
}